// Round 1
// baseline (211.195 us; speedup 1.0000x reference)
//
#include <hip/hip_runtime.h>
#include <stdint.h>

// Problem constants
#define B_SZ 8
#define T_SZ 1024
#define DM   768
#define NH   12
#define DH   64
#define NTOK (B_SZ * T_SZ)   // 8192
#define NOUT (NTOK * DM)     // 6291456

typedef unsigned short u16;
typedef __attribute__((ext_vector_type(8))) short short8;   // 8 bf16 (4 VGPRs) MFMA frag
typedef __attribute__((ext_vector_type(4))) short short4v;
typedef __attribute__((ext_vector_type(4))) float f32x4;

#define MFMA16x16x32 __builtin_amdgcn_mfma_f32_16x16x32_bf16

__device__ __forceinline__ u16 f2bf(float f) {
    unsigned u = __builtin_bit_cast(unsigned, f);
    u += 0x7fffu + ((u >> 16) & 1u);   // RNE
    return (u16)(u >> 16);
}

// CK-proven pattern: integer-cast to AS1/AS3 pointers for the direct-to-LDS load.
__device__ __forceinline__ void gload16(const void* g, void* l) {
    __builtin_amdgcn_global_load_lds(
        (const __attribute__((address_space(1))) unsigned int*)(unsigned long long)(uintptr_t)g,
        (__attribute__((address_space(3))) unsigned int*)(unsigned int)(uintptr_t)l,
        16, 0, 0);
}

// ---------------- fp32 -> bf16 elementwise ----------------
__global__ __launch_bounds__(256) void cvt_bf16_kernel(const float* __restrict__ in,
                                                       u16* __restrict__ out, int n) {
    int i = (blockIdx.x * 256 + threadIdx.x) * 4;
    if (i >= n) return;
    f32x4 v = *(const f32x4*)(in + i);
    short4v o;
    o.x = (short)f2bf(v.x); o.y = (short)f2bf(v.y);
    o.z = (short)f2bf(v.z); o.w = (short)f2bf(v.w);
    *(short4v*)(out + i) = o;
}

// ---------------- transpose fp32 [R][C] -> bf16 [C][R] ----------------
__global__ __launch_bounds__(256) void transpose_bf16_kernel(const float* __restrict__ in,
                                                             u16* __restrict__ out,
                                                             int R, int C) {
    __shared__ float tile[32][33];
    int tx = threadIdx.x & 31, ty = threadIdx.x >> 5;   // 32 x 8
    int c0 = blockIdx.x * 32, r0 = blockIdx.y * 32;
    for (int i = ty; i < 32; i += 8)
        tile[i][tx] = in[(size_t)(r0 + i) * C + c0 + tx];
    __syncthreads();
    for (int i = ty; i < 32; i += 8)
        out[(size_t)(c0 + i) * R + r0 + tx] = f2bf(tile[tx][i]);
}

// ---------------- bf16 GEMM, K=768, 128x128 tile, m97 structure ----------------
// A [M][768] bf16 row-major, BT [N][768] bf16 (B transposed).
// EPI 0: QKV epilogue (bias; Q*0.125 -> qbf[B,H,T,d]; K -> outK fp32 + kbf;
//        V -> outV fp32 + vtb bf16 transposed [B,H,d,T])
// EPI 1: proj epilogue (bias; fp32 -> outP [M][768])
template <int EPI>
__global__ __launch_bounds__(256) void gemm_k768_kernel(
    const u16* __restrict__ A, const u16* __restrict__ BT, const float* __restrict__ bias,
    u16* __restrict__ qbf, u16* __restrict__ kbf, u16* __restrict__ vtb,
    float* __restrict__ outK, float* __restrict__ outV, float* __restrict__ outP)
{
    __shared__ alignas(16) u16 As[128 * 32];   // 8 KB, rows of 32 bf16
    __shared__ alignas(16) u16 Bs[128 * 32];
    const int t   = threadIdx.x;
    const int wid = t >> 6, l = t & 63;
    const int lr  = l & 15, g = l >> 4;
    const int m0  = blockIdx.x * 128, n0 = blockIdx.y * 128;
    const int wm  = (wid >> 1) * 64, wn = (wid & 1) * 64;

    // staging: virtual tid v in [0,512): row = v>>2 (x2 calls), 16B col chunk = v&3
    const u16* ga0 = A  + (size_t)(m0 + (t >> 2)) * 768 + (t & 3) * 8;
    const u16* gb0 = BT + (size_t)(n0 + (t >> 2)) * 768 + (t & 3) * 8;
    u16* la0 = As + t * 8;
    u16* lb0 = Bs + t * 8;

    f32x4 acc[4][4] = {};
    for (int k0 = 0; k0 < 768; k0 += 32) {
        gload16(ga0 + k0,            la0);
        gload16(ga0 + 64 * 768 + k0, la0 + 2048);
        gload16(gb0 + k0,            lb0);
        gload16(gb0 + 64 * 768 + k0, lb0 + 2048);
        __syncthreads();   // compiler drains vmcnt before barrier
        short8 af[4], bfr[4];
        #pragma unroll
        for (int i = 0; i < 4; ++i)
            af[i] = *(const short8*)(As + (wm + i * 16 + lr) * 32 + g * 8);
        #pragma unroll
        for (int j = 0; j < 4; ++j)
            bfr[j] = *(const short8*)(Bs + (wn + j * 16 + lr) * 32 + g * 8);
        #pragma unroll
        for (int i = 0; i < 4; ++i)
            #pragma unroll
            for (int j = 0; j < 4; ++j)
                acc[i][j] = MFMA16x16x32(af[i], bfr[j], acc[i][j], 0, 0, 0);
        __syncthreads();
    }

    // C/D layout: col = lane&15, row = (lane>>4)*4 + reg  [verified m89/m91]
    #pragma unroll
    for (int j = 0; j < 4; ++j) {
        const int n = n0 + wn + j * 16 + lr;
        const float bn = bias[n];
        if (EPI == 0) {
            const int which = n / 768;           // 0=Q,1=K,2=V (wave-uniform)
            const int hd = n - which * 768;
            const int h = hd >> 6, dd = hd & 63;
            #pragma unroll
            for (int i = 0; i < 4; ++i) {
                #pragma unroll
                for (int r = 0; r < 4; ++r) {
                    const int m = m0 + wm + i * 16 + g * 4 + r;
                    const int b = m >> 10, tt = m & 1023;
                    const int idx = ((b * 12 + h) * 1024 + tt) * 64 + dd;
                    const float v = acc[i][j][r] + bn;
                    if (which == 0) {
                        qbf[idx] = f2bf(v * 0.125f);          // fold 1/sqrt(64)
                    } else if (which == 1) {
                        outK[idx] = v; kbf[idx] = f2bf(v);
                    } else {
                        outV[idx] = v;
                        vtb[(b * 12 + h) * 65536 + dd * 1024 + tt] = f2bf(v);
                    }
                }
            }
        } else {
            #pragma unroll
            for (int i = 0; i < 4; ++i)
                #pragma unroll
                for (int r = 0; r < 4; ++r) {
                    const int m = m0 + wm + i * 16 + g * 4 + r;
                    outP[(size_t)m * 768 + n] = acc[i][j][r] + bn;
                }
        }
    }
}

// ---------------- causal flash attention ----------------
// grid (B*H, T/64), 4 waves/block, 16 q-rows per wave. Swapped QK^T:
// scoresT = mfma(A=K[kt][d], B=Q^T) -> D[kt][q]: lane q = l&15, kt = g*4+r.
// PV: out = mfma(A=P[q][kt] via LDS re-layout, B=V[kt][d] read from V^T).
__global__ __launch_bounds__(256) void attn_kernel(
    const u16* __restrict__ Qb, const u16* __restrict__ Kb,
    const u16* __restrict__ Vt, u16* __restrict__ Ob)
{
    __shared__ alignas(16) u16 Pl[4][16 * 40];  // per-wave 16 rows x 40 u16 (80B rows, <=2-way conflicts)
    const int bh = blockIdx.x;
    const int wid = threadIdx.x >> 6, l = threadIdx.x & 63;
    const int q = l & 15, g = l >> 4;
    const int qbase = blockIdx.y * 64 + wid * 16;
    u16* P = Pl[wid];

    const u16* Qp = Qb + ((size_t)bh * 1024 + qbase + q) * 64 + g * 8;
    const short8 bq0 = *(const short8*)(Qp);
    const short8 bq1 = *(const short8*)(Qp + 32);
    const u16* Kp = Kb + (size_t)bh * 65536;
    const u16* Vp = Vt + (size_t)bh * 65536;

    f32x4 oacc[4] = {};
    float mrow = -__builtin_inff(), lsum = 0.f;
    const int nblk = (qbase >> 5) + 1;   // causal: skip fully-masked 32-blocks
    for (int kb = 0; kb < nblk; ++kb) {
        const int kt0 = kb << 5;
        const u16* K0 = Kp + (size_t)(kt0 + q) * 64 + g * 8;
        const short8 a00 = *(const short8*)(K0);
        const short8 a01 = *(const short8*)(K0 + 32);
        const short8 a10 = *(const short8*)(K0 + 1024);
        const short8 a11 = *(const short8*)(K0 + 1024 + 32);
        f32x4 s0 = {}, s1 = {};
        s0 = MFMA16x16x32(a00, bq0, s0, 0, 0, 0);
        s0 = MFMA16x16x32(a01, bq1, s0, 0, 0, 0);
        s1 = MFMA16x16x32(a10, bq0, s1, 0, 0, 0);
        s1 = MFMA16x16x32(a11, bq1, s1, 0, 0, 0);
        if (kb == nblk - 1) {            // only diagonal block needs masking
            const int qg = qbase + q;
            #pragma unroll
            for (int r = 0; r < 4; ++r) {
                if (kt0 + g * 4 + r > qg)      s0[r] = -__builtin_inff();
                if (kt0 + 16 + g * 4 + r > qg) s1[r] = -__builtin_inff();
            }
        }
        float tm = fmaxf(fmaxf(fmaxf(s0[0], s0[1]), fmaxf(s0[2], s0[3])),
                         fmaxf(fmaxf(s1[0], s1[1]), fmaxf(s1[2], s1[3])));
        tm = fmaxf(tm, __shfl_xor(tm, 16));
        tm = fmaxf(tm, __shfl_xor(tm, 32));
        const float mnew = fmaxf(mrow, tm);
        const float sc = exp2f((mrow - mnew) * 1.44269504f);
        float p0[4], p1[4], rs = 0.f;
        #pragma unroll
        for (int r = 0; r < 4; ++r) { p0[r] = exp2f((s0[r] - mnew) * 1.44269504f); rs += p0[r]; }
        #pragma unroll
        for (int r = 0; r < 4; ++r) { p1[r] = exp2f((s1[r] - mnew) * 1.44269504f); rs += p1[r]; }
        rs += __shfl_xor(rs, 16);
        rs += __shfl_xor(rs, 32);
        lsum = lsum * sc + rs;
        mrow = mnew;
        // P[q][kt] bf16 into padded LDS (row stride 40 u16 = 80 B)
        short4v w0, w1;
        w0.x = (short)f2bf(p0[0]); w0.y = (short)f2bf(p0[1]);
        w0.z = (short)f2bf(p0[2]); w0.w = (short)f2bf(p0[3]);
        w1.x = (short)f2bf(p1[0]); w1.y = (short)f2bf(p1[1]);
        w1.z = (short)f2bf(p1[2]); w1.w = (short)f2bf(p1[3]);
        *(short4v*)(P + q * 40 + g * 4) = w0;
        *(short4v*)(P + q * 40 + 16 + g * 4) = w1;
        // rescale O accumulators (lane row = g*4+r; scale lives at lane q=g*4+r)
        const float sc0 = __shfl(sc, g * 4 + 0);
        const float sc1 = __shfl(sc, g * 4 + 1);
        const float sc2 = __shfl(sc, g * 4 + 2);
        const float sc3 = __shfl(sc, g * 4 + 3);
        #pragma unroll
        for (int dt = 0; dt < 4; ++dt) {
            oacc[dt][0] *= sc0; oacc[dt][1] *= sc1;
            oacc[dt][2] *= sc2; oacc[dt][3] *= sc3;
        }
        // PV: A-frag P[q][g*8..g*8+7], B-frag V[kt][d] from V^T rows (contiguous)
        const short8 pf = *(const short8*)(P + q * 40 + g * 8);
        #pragma unroll
        for (int dt = 0; dt < 4; ++dt) {
            const short8 bv = *(const short8*)(Vp + (size_t)(dt * 16 + q) * 1024 + kt0 + g * 8);
            oacc[dt] = MFMA16x16x32(pf, bv, oacc[dt], 0, 0, 0);
        }
    }
    const float li0 = 1.f / __shfl(lsum, g * 4 + 0);
    const float li1 = 1.f / __shfl(lsum, g * 4 + 1);
    const float li2 = 1.f / __shfl(lsum, g * 4 + 2);
    const float li3 = 1.f / __shfl(lsum, g * 4 + 3);
    const int b = bh / 12, h = bh - (bh / 12) * 12;
    #pragma unroll
    for (int dt = 0; dt < 4; ++dt) {
        const size_t base = (size_t)(b * 1024 + qbase + g * 4) * 768 + h * 64 + dt * 16 + q;
        Ob[base]           = f2bf(oacc[dt][0] * li0);
        Ob[base + 768]     = f2bf(oacc[dt][1] * li1);
        Ob[base + 2 * 768] = f2bf(oacc[dt][2] * li2);
        Ob[base + 3 * 768] = f2bf(oacc[dt][3] * li3);
    }
}

extern "C" void kernel_launch(void* const* d_in, const int* in_sizes, int n_in,
                              void* d_out, int out_size, void* d_ws, size_t ws_size,
                              hipStream_t stream) {
    const float* hs = (const float*)d_in[0];   // [8,1024,768]
    const float* Wa = (const float*)d_in[1];   // [768,2304]
    const float* ba = (const float*)d_in[2];   // [2304]
    const float* Wp = (const float*)d_in[3];   // [768,768]
    const float* bp = (const float*)d_in[4];   // [768]
    float* out = (float*)d_out;                // out | K | V  (each NOUT fp32)

    u16* ws  = (u16*)d_ws;                     // ~67.6 MB total bf16 scratch
    u16* Xbf = ws;                             // [8192][768]
    u16* WaT = Xbf + NOUT;                     // [2304][768]
    u16* WpT = WaT + 768 * 2304;               // [768][768]
    u16* Qbf = WpT + 768 * 768;                // [B,H,T,64] (pre-scaled by 1/8)
    u16* Kbf = Qbf + NOUT;                     // [B,H,T,64]
    u16* VTb = Kbf + NOUT;                     // [B,H,64,T]
    u16* Obf = VTb + NOUT;                     // [8192][768]

    cvt_bf16_kernel<<<NOUT / 1024, 256, 0, stream>>>(hs, Xbf, NOUT);
    transpose_bf16_kernel<<<dim3(2304 / 32, 768 / 32), 256, 0, stream>>>(Wa, WaT, 768, 2304);
    transpose_bf16_kernel<<<dim3(768 / 32, 768 / 32), 256, 0, stream>>>(Wp, WpT, 768, 768);
    gemm_k768_kernel<0><<<dim3(64, 18), 256, 0, stream>>>(
        Xbf, WaT, ba, Qbf, Kbf, VTb, out + NOUT, out + 2 * (size_t)NOUT, nullptr);
    attn_kernel<<<dim3(96, 16), 256, 0, stream>>>(Qbf, Kbf, VTb, Obf);
    gemm_k768_kernel<1><<<dim3(64, 6), 256, 0, stream>>>(
        Obf, WpT, bp, nullptr, nullptr, nullptr, nullptr, nullptr, out);
}

// Round 2
// 195.712 us; speedup vs baseline: 1.0791x; 1.0791x over previous
//
#include <hip/hip_runtime.h>
#include <stdint.h>

// Problem constants
#define B_SZ 8
#define T_SZ 1024
#define DM   768
#define NH   12
#define DH   64
#define NTOK (B_SZ * T_SZ)   // 8192
#define NOUT (NTOK * DM)     // 6291456
#define INF  __builtin_inff()

typedef unsigned short u16;
typedef __attribute__((ext_vector_type(8))) short short8;   // 8 bf16 (4 VGPRs) MFMA frag
typedef __attribute__((ext_vector_type(4))) short short4v;
typedef __attribute__((ext_vector_type(4))) float f32x4;

#define MFMA16x16x32 __builtin_amdgcn_mfma_f32_16x16x32_bf16

__device__ __forceinline__ u16 f2bf(float f) {
    unsigned u = __builtin_bit_cast(unsigned, f);
    u += 0x7fffu + ((u >> 16) & 1u);   // RNE
    return (u16)(u >> 16);
}

// CK-proven pattern: integer-cast to AS1/AS3 pointers for the direct-to-LDS load.
__device__ __forceinline__ void gload16(const void* g, void* l) {
    __builtin_amdgcn_global_load_lds(
        (const __attribute__((address_space(1))) unsigned int*)(unsigned long long)(uintptr_t)g,
        (__attribute__((address_space(3))) unsigned int*)(unsigned int)(uintptr_t)l,
        16, 0, 0);
}

// ---------------- fp32 -> bf16 elementwise ----------------
__global__ __launch_bounds__(256) void cvt_bf16_kernel(const float* __restrict__ in,
                                                       u16* __restrict__ out, int n) {
    int i = (blockIdx.x * 256 + threadIdx.x) * 4;
    if (i >= n) return;
    f32x4 v = *(const f32x4*)(in + i);
    short4v o;
    o.x = (short)f2bf(v.x); o.y = (short)f2bf(v.y);
    o.z = (short)f2bf(v.z); o.w = (short)f2bf(v.w);
    *(short4v*)(out + i) = o;
}

// ---------------- transpose fp32 [R][C] -> bf16 [C][R] ----------------
__global__ __launch_bounds__(256) void transpose_bf16_kernel(const float* __restrict__ in,
                                                             u16* __restrict__ out,
                                                             int R, int C) {
    __shared__ float tile[32][33];
    int tx = threadIdx.x & 31, ty = threadIdx.x >> 5;   // 32 x 8
    int c0 = blockIdx.x * 32, r0 = blockIdx.y * 32;
    for (int i = ty; i < 32; i += 8)
        tile[i][tx] = in[(size_t)(r0 + i) * C + c0 + tx];
    __syncthreads();
    for (int i = ty; i < 32; i += 8)
        out[(size_t)(c0 + i) * R + r0 + tx] = f2bf(tile[tx][i]);
}

// ---------------- bf16 GEMM, K=768, 128x128 tile, m97 structure ----------------
template <int EPI>
__global__ __launch_bounds__(256) void gemm_k768_kernel(
    const u16* __restrict__ A, const u16* __restrict__ BT, const float* __restrict__ bias,
    u16* __restrict__ qbf, u16* __restrict__ kbf, u16* __restrict__ vtb,
    float* __restrict__ outK, float* __restrict__ outV, float* __restrict__ outP)
{
    __shared__ alignas(16) u16 As[128 * 32];   // 8 KB, rows of 32 bf16
    __shared__ alignas(16) u16 Bs[128 * 32];
    const int t   = threadIdx.x;
    const int wid = t >> 6, l = t & 63;
    const int lr  = l & 15, g = l >> 4;
    const int m0  = blockIdx.x * 128, n0 = blockIdx.y * 128;
    const int wm  = (wid >> 1) * 64, wn = (wid & 1) * 64;

    const u16* ga0 = A  + (size_t)(m0 + (t >> 2)) * 768 + (t & 3) * 8;
    const u16* gb0 = BT + (size_t)(n0 + (t >> 2)) * 768 + (t & 3) * 8;
    u16* la0 = As + t * 8;
    u16* lb0 = Bs + t * 8;

    f32x4 acc[4][4] = {};
    for (int k0 = 0; k0 < 768; k0 += 32) {
        gload16(ga0 + k0,            la0);
        gload16(ga0 + 64 * 768 + k0, la0 + 2048);
        gload16(gb0 + k0,            lb0);
        gload16(gb0 + 64 * 768 + k0, lb0 + 2048);
        __syncthreads();
        short8 af[4], bfr[4];
        #pragma unroll
        for (int i = 0; i < 4; ++i)
            af[i] = *(const short8*)(As + (wm + i * 16 + lr) * 32 + g * 8);
        #pragma unroll
        for (int j = 0; j < 4; ++j)
            bfr[j] = *(const short8*)(Bs + (wn + j * 16 + lr) * 32 + g * 8);
        #pragma unroll
        for (int i = 0; i < 4; ++i)
            #pragma unroll
            for (int j = 0; j < 4; ++j)
                acc[i][j] = MFMA16x16x32(af[i], bfr[j], acc[i][j], 0, 0, 0);
        __syncthreads();
    }

    // C/D layout: col = lane&15, row = (lane>>4)*4 + reg  [verified m89/m91]
    #pragma unroll
    for (int j = 0; j < 4; ++j) {
        const int n = n0 + wn + j * 16 + lr;
        const float bn = bias[n];
        if (EPI == 0) {
            const int which = n / 768;           // 0=Q,1=K,2=V (wave-uniform)
            const int hd = n - which * 768;
            const int h = hd >> 6, dd = hd & 63;
            #pragma unroll
            for (int i = 0; i < 4; ++i) {
                #pragma unroll
                for (int r = 0; r < 4; ++r) {
                    const int m = m0 + wm + i * 16 + g * 4 + r;
                    const int b = m >> 10, tt = m & 1023;
                    const int idx = ((b * 12 + h) * 1024 + tt) * 64 + dd;
                    const float v = acc[i][j][r] + bn;
                    if (which == 0) {
                        // fold 1/sqrt(64) and log2(e) so attn exp2 needs no mul
                        qbf[idx] = f2bf(v * (0.125f * 1.44269504f));
                    } else if (which == 1) {
                        outK[idx] = v; kbf[idx] = f2bf(v);
                    } else {
                        outV[idx] = v;
                        vtb[(b * 12 + h) * 65536 + dd * 1024 + tt] = f2bf(v);
                    }
                }
            }
        } else {
            #pragma unroll
            for (int i = 0; i < 4; ++i)
                #pragma unroll
                for (int r = 0; r < 4; ++r) {
                    const int m = m0 + wm + i * 16 + g * 4 + r;
                    outP[(size_t)m * 768 + n] = acc[i][j][r] + bn;
                }
        }
    }
}

// ---------------- causal flash attention, balanced + KVBLK=64 ----------------
// grid (96, 8), 4 waves. Block y handles q-tiles y and 15-y (uniform 17 rounds).
// Wave: 16 q-rows. Swapped QK^T: D[kt][q], col=q lane-local. Swapped PV:
// mfma(A=V^T, B=P^T) -> D[d][q], col=q lane-local => sc/lsum need no broadcast.
__global__ __launch_bounds__(256, 3) void attn_kernel(
    const u16* __restrict__ Qb, const u16* __restrict__ Kb,
    const u16* __restrict__ Vt, u16* __restrict__ Ob)
{
    __shared__ alignas(16) u16 Pl[4][16 * 72];   // per-wave P: 16 rows x (64+8 pad) u16
    const int bh = blockIdx.x;
    const int wid = threadIdx.x >> 6, l = threadIdx.x & 63;
    const int c = l & 15, g = l >> 4;
    u16* P = Pl[wid];
    const u16* Kp = Kb + (size_t)bh * 65536;     // [T][64]
    const u16* Vp = Vt + (size_t)bh * 65536;     // [64][T]
    const int b = bh / 12, h = bh - (bh / 12) * 12;

    #pragma unroll 1
    for (int pass = 0; pass < 2; ++pass) {
        const int tile = pass ? (15 - blockIdx.y) : blockIdx.y;
        const int qbase = tile * 64 + wid * 16;
        const int qg = qbase + c;                // this lane's q column
        const u16* Qp = Qb + ((size_t)bh * 1024 + qg) * 64 + g * 8;
        const short8 bq0 = *(const short8*)(Qp);
        const short8 bq1 = *(const short8*)(Qp + 32);

        f32x4 oacc[4] = {};
        float mrow = -INF, lsum = 0.f;
        const int nb = tile + 1;                 // 64-wide KV blocks

        short8 ka[8];                            // K frags for current kb
        #pragma unroll
        for (int j = 0; j < 4; ++j) {
            const u16* kp = Kp + (size_t)(j * 16 + c) * 64 + g * 8;
            ka[2 * j]     = *(const short8*)(kp);
            ka[2 * j + 1] = *(const short8*)(kp + 32);
        }

        #pragma unroll 1
        for (int kb = 0; kb < nb; ++kb) {
            const int kt0 = kb << 6;
            // issue V loads (current) and K loads (next) before the long chain
            short8 vb[8];
            #pragma unroll
            for (int dt = 0; dt < 4; ++dt) {
                const u16* vp = Vp + (size_t)(dt * 16 + c) * 1024 + kt0 + g * 8;
                vb[2 * dt]     = *(const short8*)(vp);
                vb[2 * dt + 1] = *(const short8*)(vp + 32);
            }
            short8 kn[8];
            if (kb + 1 < nb) {
                #pragma unroll
                for (int j = 0; j < 4; ++j) {
                    const u16* kp = Kp + (size_t)(kt0 + 64 + j * 16 + c) * 64 + g * 8;
                    kn[2 * j]     = *(const short8*)(kp);
                    kn[2 * j + 1] = *(const short8*)(kp + 32);
                }
            }
            // QK^T: s[j] = scores for kt chunk j (rows kt0+16j .. +15)
            f32x4 s[4] = {};
            __builtin_amdgcn_s_setprio(1);
            #pragma unroll
            for (int j = 0; j < 4; ++j) {
                s[j] = MFMA16x16x32(ka[2 * j],     bq0, s[j], 0, 0, 0);
                s[j] = MFMA16x16x32(ka[2 * j + 1], bq1, s[j], 0, 0, 0);
            }
            __builtin_amdgcn_s_setprio(0);
            if (kb == nb - 1) {                  // only diagonal block masks
                #pragma unroll
                for (int j = 0; j < 4; ++j)
                    #pragma unroll
                    for (int r = 0; r < 4; ++r)
                        if (kt0 + j * 16 + g * 4 + r > qg) s[j][r] = -INF;
            }
            // softmax (scores already in log2 units)
            float tm = -INF;
            #pragma unroll
            for (int j = 0; j < 4; ++j)
                #pragma unroll
                for (int r = 0; r < 4; ++r) tm = fmaxf(tm, s[j][r]);
            tm = fmaxf(tm, __shfl_xor(tm, 16));
            tm = fmaxf(tm, __shfl_xor(tm, 32));
            const float mnew = fmaxf(mrow, tm);
            const float sc = exp2f(mrow - mnew);
            mrow = mnew;
            float rs = 0.f;
            float p[4][4];
            #pragma unroll
            for (int j = 0; j < 4; ++j)
                #pragma unroll
                for (int r = 0; r < 4; ++r) {
                    p[j][r] = exp2f(s[j][r] - mnew);
                    rs += p[j][r];
                }
            rs += __shfl_xor(rs, 16);
            rs += __shfl_xor(rs, 32);
            lsum = lsum * sc + rs;
            // P[q=c][kt] bf16 -> LDS (row stride 72 u16 = 144 B)
            #pragma unroll
            for (int j = 0; j < 4; ++j) {
                short4v w;
                w.x = (short)f2bf(p[j][0]); w.y = (short)f2bf(p[j][1]);
                w.z = (short)f2bf(p[j][2]); w.w = (short)f2bf(p[j][3]);
                *(short4v*)(P + c * 72 + j * 16 + g * 4) = w;
            }
            // rescale O (sc is lane-local: col=q layout)
            #pragma unroll
            for (int dt = 0; dt < 4; ++dt) {
                oacc[dt][0] *= sc; oacc[dt][1] *= sc;
                oacc[dt][2] *= sc; oacc[dt][3] *= sc;
            }
            // PV: A = V^T rows (d), B = P^T -> D[d][q]
            const short8 pf0 = *(const short8*)(P + c * 72 + g * 8);
            const short8 pf1 = *(const short8*)(P + c * 72 + 32 + g * 8);
            __builtin_amdgcn_s_setprio(1);
            #pragma unroll
            for (int dt = 0; dt < 4; ++dt) {
                oacc[dt] = MFMA16x16x32(vb[2 * dt],     pf0, oacc[dt], 0, 0, 0);
                oacc[dt] = MFMA16x16x32(vb[2 * dt + 1], pf1, oacc[dt], 0, 0, 0);
            }
            __builtin_amdgcn_s_setprio(0);
            if (kb + 1 < nb) {
                #pragma unroll
                for (int i = 0; i < 8; ++i) ka[i] = kn[i];
            }
        }
        const float li = 1.f / lsum;             // lane-local
        #pragma unroll
        for (int dt = 0; dt < 4; ++dt) {
            short4v o;
            o.x = (short)f2bf(oacc[dt][0] * li);
            o.y = (short)f2bf(oacc[dt][1] * li);
            o.z = (short)f2bf(oacc[dt][2] * li);
            o.w = (short)f2bf(oacc[dt][3] * li);
            *(short4v*)(Ob + (size_t)(b * 1024 + qg) * 768 + h * 64 + dt * 16 + g * 4) = o;
        }
    }
}

extern "C" void kernel_launch(void* const* d_in, const int* in_sizes, int n_in,
                              void* d_out, int out_size, void* d_ws, size_t ws_size,
                              hipStream_t stream) {
    const float* hs = (const float*)d_in[0];   // [8,1024,768]
    const float* Wa = (const float*)d_in[1];   // [768,2304]
    const float* ba = (const float*)d_in[2];   // [2304]
    const float* Wp = (const float*)d_in[3];   // [768,768]
    const float* bp = (const float*)d_in[4];   // [768]
    float* out = (float*)d_out;                // out | K | V  (each NOUT fp32)

    u16* ws  = (u16*)d_ws;
    u16* Xbf = ws;                             // [8192][768]
    u16* WaT = Xbf + NOUT;                     // [2304][768]
    u16* WpT = WaT + 768 * 2304;               // [768][768]
    u16* Qbf = WpT + 768 * 768;                // [B,H,T,64] (pre-scaled by 0.125*log2e)
    u16* Kbf = Qbf + NOUT;                     // [B,H,T,64]
    u16* VTb = Kbf + NOUT;                     // [B,H,64,T]
    u16* Obf = VTb + NOUT;                     // [8192][768]

    cvt_bf16_kernel<<<NOUT / 1024, 256, 0, stream>>>(hs, Xbf, NOUT);
    transpose_bf16_kernel<<<dim3(2304 / 32, 768 / 32), 256, 0, stream>>>(Wa, WaT, 768, 2304);
    transpose_bf16_kernel<<<dim3(768 / 32, 768 / 32), 256, 0, stream>>>(Wp, WpT, 768, 768);
    gemm_k768_kernel<0><<<dim3(64, 18), 256, 0, stream>>>(
        Xbf, WaT, ba, Qbf, Kbf, VTb, out + NOUT, out + 2 * (size_t)NOUT, nullptr);
    attn_kernel<<<dim3(96, 8), 256, 0, stream>>>(Qbf, Kbf, VTb, Obf);
    gemm_k768_kernel<1><<<dim3(64, 6), 256, 0, stream>>>(
        Obf, WpT, bp, nullptr, nullptr, nullptr, nullptr, nullptr, out);
}

// Round 3
// 136.591 us; speedup vs baseline: 1.5462x; 1.4328x over previous
//
#include <hip/hip_runtime.h>
#include <stdint.h>

// Problem constants
#define B_SZ 8
#define T_SZ 1024
#define DM   768
#define NH   12
#define DH   64
#define NTOK (B_SZ * T_SZ)   // 8192
#define NOUT (NTOK * DM)     // 6291456
#define INF  __builtin_inff()

typedef unsigned short u16;
typedef __attribute__((ext_vector_type(8))) short short8;   // 8 bf16 (4 VGPRs) MFMA frag
typedef __attribute__((ext_vector_type(4))) short short4v;
typedef __attribute__((ext_vector_type(4))) float f32x4;

#define MFMA16x16x32 __builtin_amdgcn_mfma_f32_16x16x32_bf16

__device__ __forceinline__ u16 f2bf(float f) {
    unsigned u = __builtin_bit_cast(unsigned, f);
    u += 0x7fffu + ((u >> 16) & 1u);   // RNE
    return (u16)(u >> 16);
}

__device__ __forceinline__ f32x4 max4(f32x4 a, f32x4 b) {
    f32x4 r; r.x = fmaxf(a.x, b.x); r.y = fmaxf(a.y, b.y);
    r.z = fmaxf(a.z, b.z); r.w = fmaxf(a.w, b.w); return r;
}
__device__ __forceinline__ f32x4 add4(f32x4 a, f32x4 b) {
    f32x4 r; r.x = a.x + b.x; r.y = a.y + b.y;
    r.z = a.z + b.z; r.w = a.w + b.w; return r;
}

// CK-proven pattern: integer-cast to AS1/AS3 pointers for the direct-to-LDS load.
__device__ __forceinline__ void gload16(const void* g, void* l) {
    __builtin_amdgcn_global_load_lds(
        (const __attribute__((address_space(1))) unsigned int*)(unsigned long long)(uintptr_t)g,
        (__attribute__((address_space(3))) unsigned int*)(unsigned int)(uintptr_t)l,
        16, 0, 0);
}

// ---------------- fp32 -> bf16 elementwise ----------------
__global__ __launch_bounds__(256) void cvt_bf16_kernel(const float* __restrict__ in,
                                                       u16* __restrict__ out, int n) {
    int i = (blockIdx.x * 256 + threadIdx.x) * 4;
    if (i >= n) return;
    f32x4 v = *(const f32x4*)(in + i);
    short4v o;
    o.x = (short)f2bf(v.x); o.y = (short)f2bf(v.y);
    o.z = (short)f2bf(v.z); o.w = (short)f2bf(v.w);
    *(short4v*)(out + i) = o;
}

// ---------------- transpose fp32 [R][C] -> bf16 [C][R] ----------------
__global__ __launch_bounds__(256) void transpose_bf16_kernel(const float* __restrict__ in,
                                                             u16* __restrict__ out,
                                                             int R, int C) {
    __shared__ float tile[32][33];
    int tx = threadIdx.x & 31, ty = threadIdx.x >> 5;   // 32 x 8
    int c0 = blockIdx.x * 32, r0 = blockIdx.y * 32;
    for (int i = ty; i < 32; i += 8)
        tile[i][tx] = in[(size_t)(r0 + i) * C + c0 + tx];
    __syncthreads();
    for (int i = ty; i < 32; i += 8)
        out[(size_t)(c0 + i) * R + r0 + tx] = f2bf(tile[tx][i]);
}

// ---------------- bf16 GEMM, K=768, 128x128 tile, m97 structure ----------------
template <int EPI>
__global__ __launch_bounds__(256) void gemm_k768_kernel(
    const u16* __restrict__ A, const u16* __restrict__ BT, const float* __restrict__ bias,
    u16* __restrict__ qbf, u16* __restrict__ kbf, u16* __restrict__ vtb,
    float* __restrict__ outK, float* __restrict__ outV, float* __restrict__ outP)
{
    __shared__ alignas(16) u16 As[128 * 32];   // 8 KB, rows of 32 bf16
    __shared__ alignas(16) u16 Bs[128 * 32];
    const int t   = threadIdx.x;
    const int wid = t >> 6, l = t & 63;
    const int lr  = l & 15, g = l >> 4;
    const int m0  = blockIdx.x * 128, n0 = blockIdx.y * 128;
    const int wm  = (wid >> 1) * 64, wn = (wid & 1) * 64;

    const u16* ga0 = A  + (size_t)(m0 + (t >> 2)) * 768 + (t & 3) * 8;
    const u16* gb0 = BT + (size_t)(n0 + (t >> 2)) * 768 + (t & 3) * 8;
    u16* la0 = As + t * 8;
    u16* lb0 = Bs + t * 8;

    f32x4 acc[4][4] = {};
    for (int k0 = 0; k0 < 768; k0 += 32) {
        gload16(ga0 + k0,            la0);
        gload16(ga0 + 64 * 768 + k0, la0 + 2048);
        gload16(gb0 + k0,            lb0);
        gload16(gb0 + 64 * 768 + k0, lb0 + 2048);
        __syncthreads();
        short8 af[4], bfr[4];
        #pragma unroll
        for (int i = 0; i < 4; ++i)
            af[i] = *(const short8*)(As + (wm + i * 16 + lr) * 32 + g * 8);
        #pragma unroll
        for (int j = 0; j < 4; ++j)
            bfr[j] = *(const short8*)(Bs + (wn + j * 16 + lr) * 32 + g * 8);
        #pragma unroll
        for (int i = 0; i < 4; ++i)
            #pragma unroll
            for (int j = 0; j < 4; ++j)
                acc[i][j] = MFMA16x16x32(af[i], bfr[j], acc[i][j], 0, 0, 0);
        __syncthreads();
    }

    // C/D layout: col = lane&15, row = (lane>>4)*4 + reg  [verified m89/m91]
    #pragma unroll
    for (int j = 0; j < 4; ++j) {
        const int n = n0 + wn + j * 16 + lr;
        const float bn = bias[n];
        if (EPI == 0) {
            const int which = n / 768;           // 0=Q,1=K,2=V (wave-uniform)
            const int hd = n - which * 768;
            const int h = hd >> 6, dd = hd & 63;
            #pragma unroll
            for (int i = 0; i < 4; ++i) {
                #pragma unroll
                for (int r = 0; r < 4; ++r) {
                    const int m = m0 + wm + i * 16 + g * 4 + r;
                    const int b = m >> 10, tt = m & 1023;
                    const int idx = ((b * 12 + h) * 1024 + tt) * 64 + dd;
                    const float v = acc[i][j][r] + bn;
                    if (which == 0) {
                        // fold 1/sqrt(64) and log2(e) so attn exp2 needs no mul
                        qbf[idx] = f2bf(v * (0.125f * 1.44269504f));
                    } else if (which == 1) {
                        outK[idx] = v; kbf[idx] = f2bf(v);
                    } else {
                        outV[idx] = v;
                        vtb[(b * 12 + h) * 65536 + dd * 1024 + tt] = f2bf(v);
                    }
                }
            }
        } else {
            #pragma unroll
            for (int i = 0; i < 4; ++i)
                #pragma unroll
                for (int r = 0; r < 4; ++r) {
                    const int m = m0 + wm + i * 16 + g * 4 + r;
                    outP[(size_t)m * 768 + n] = acc[i][j][r] + bn;
                }
        }
    }
}

// ---------------- causal flash attention, LDS-staged 2-phase pipeline ----------------
// grid (96, 8), 4 waves. Block y handles q-tiles y and 15-y (uniform 17 rounds).
// K/V tiles (64 kt x 64 d bf16, 8 KB each) double-buffered in LDS via
// global_load_lds with XOR chunk-swizzle (chunk ^= row&7) applied on the GLOBAL
// source and on the ds_read address (both-sides rule). Wave owns 16 q columns.
__global__ __launch_bounds__(256, 3) void attn_kernel(
    const u16* __restrict__ Qb, const u16* __restrict__ Kb,
    const u16* __restrict__ Vt, u16* __restrict__ Ob)
{
    __shared__ alignas(16) u16 Ks[2][4096];     // [64 kt][8 chunks of 8 u16], swizzled
    __shared__ alignas(16) u16 Vs[2][4096];     // [64 d ][8 chunks of 8 u16], swizzled
    __shared__ alignas(16) u16 Pl[4][16 * 72];  // per-wave P: 16 q x (64+8 pad) u16
    const int bh = blockIdx.x;
    const int t = threadIdx.x;
    const int wid = t >> 6, l = t & 63;
    const int c = l & 15, g = l >> 4;
    u16* P = Pl[wid];
    const u16* Kp = Kb + (size_t)bh * 65536;    // [T][64]
    const u16* Vp = Vt + (size_t)bh * 65536;    // [64][T]
    const int b = bh / 12, h = bh - (bh / 12) * 12;

    // staging constants: thread t carries row = t>>3 (and +32), physical slot t&7,
    // whose logical chunk is (t&7) ^ (row&7)  ((row+32)&7 == row&7)
    const int srow = t >> 3;
    const int sch  = (t & 7) ^ (srow & 7);
    const u16* Ksrc0 = Kp + (size_t)srow * 64 + sch * 8;
    const u16* Ksrc1 = Kp + (size_t)(srow + 32) * 64 + sch * 8;
    const u16* Vsrc0 = Vp + (size_t)srow * 1024 + sch * 8;
    const u16* Vsrc1 = Vp + (size_t)(srow + 32) * 1024 + sch * 8;

    // fragment read offsets (u16): row c (within 16-row subtile), logical chunk g / g+4
    const int fo0 = c * 64 + ((g ^ (c & 7)) * 8);
    const int fo1 = c * 64 + (((g + 4) ^ (c & 7)) * 8);

#define STAGE(buf, kt0) do {                                        \
        gload16(Ksrc0 + (size_t)(kt0) * 64, Ks[buf] + t * 8);       \
        gload16(Ksrc1 + (size_t)(kt0) * 64, Ks[buf] + 2048 + t * 8);\
        gload16(Vsrc0 + (kt0),              Vs[buf] + t * 8);       \
        gload16(Vsrc1 + (kt0),              Vs[buf] + 2048 + t * 8);\
    } while (0)

    #pragma unroll 1
    for (int pass = 0; pass < 2; ++pass) {
        const int tile = pass ? (15 - blockIdx.y) : blockIdx.y;
        const int qbase = tile * 64 + wid * 16;
        const int qg = qbase + c;                // this lane's q column
        const u16* Qp = Qb + ((size_t)bh * 1024 + qg) * 64 + g * 8;
        const short8 bq0 = *(const short8*)(Qp);
        const short8 bq1 = *(const short8*)(Qp + 32);

        f32x4 oacc[4] = {};
        float mrow = -INF, lpart = 0.f;
        const int nb = tile + 1;                 // 64-wide KV blocks

        STAGE(0, 0);
        __syncthreads();
        int cur = 0;

        #pragma unroll 1
        for (int kb = 0; kb < nb; ++kb) {
            if (kb + 1 < nb) STAGE(cur ^ 1, (kb + 1) << 6);
            const u16* kB = Ks[cur];
            const u16* vB = Vs[cur];
            short8 af0[4], af1[4], vf0[4], vf1[4];
            #pragma unroll
            for (int j = 0; j < 4; ++j) {
                af0[j] = *(const short8*)(kB + j * 1024 + fo0);
                af1[j] = *(const short8*)(kB + j * 1024 + fo1);
            }
            #pragma unroll
            for (int dt = 0; dt < 4; ++dt) {
                vf0[dt] = *(const short8*)(vB + dt * 1024 + fo0);
                vf1[dt] = *(const short8*)(vB + dt * 1024 + fo1);
            }
            // QK^T: D[kt][q], s[j] covers kt rows j*16 + g*4 + r
            f32x4 s[4] = {};
            __builtin_amdgcn_s_setprio(1);
            #pragma unroll
            for (int j = 0; j < 4; ++j) {
                s[j] = MFMA16x16x32(af0[j], bq0, s[j], 0, 0, 0);
                s[j] = MFMA16x16x32(af1[j], bq1, s[j], 0, 0, 0);
            }
            __builtin_amdgcn_s_setprio(0);
            if (kb == nb - 1) {                  // only diagonal block masks
                const int kt0 = kb << 6;
                #pragma unroll
                for (int j = 0; j < 4; ++j)
                    #pragma unroll
                    for (int r = 0; r < 4; ++r)
                        if (kt0 + j * 16 + g * 4 + r > qg) s[j][r] = -INF;
            }
            // softmax (scores already in log2 units); tree max
            f32x4 mm = max4(max4(s[0], s[1]), max4(s[2], s[3]));
            float tm = fmaxf(fmaxf(mm.x, mm.y), fmaxf(mm.z, mm.w));
            tm = fmaxf(tm, __shfl_xor(tm, 16));
            tm = fmaxf(tm, __shfl_xor(tm, 32));
            // defer-max (T13): skip rescale while growth <= 8 (log2 units; P <= 256)
            const bool keep = (__all(tm <= mrow + 8.f) != 0);
            const float mnew = keep ? mrow : fmaxf(mrow, tm);
            if (!keep) {
                const float sc = exp2f(mrow - mnew);
                mrow = mnew;
                lpart *= sc;
                #pragma unroll
                for (int dt = 0; dt < 4; ++dt) {
                    oacc[dt][0] *= sc; oacc[dt][1] *= sc;
                    oacc[dt][2] *= sc; oacc[dt][3] *= sc;
                }
            }
            f32x4 p[4];
            #pragma unroll
            for (int j = 0; j < 4; ++j) {
                p[j].x = exp2f(s[j].x - mnew); p[j].y = exp2f(s[j].y - mnew);
                p[j].z = exp2f(s[j].z - mnew); p[j].w = exp2f(s[j].w - mnew);
            }
            f32x4 ps = add4(add4(p[0], p[1]), add4(p[2], p[3]));
            lpart += (ps.x + ps.y) + (ps.z + ps.w);   // per-lane partial (g-reduce deferred)
            // P[q=c][kt] bf16 -> LDS (row stride 72 u16 = 144 B, 2-way conflicts only)
            #pragma unroll
            for (int j = 0; j < 4; ++j) {
                short4v w;
                w.x = (short)f2bf(p[j].x); w.y = (short)f2bf(p[j].y);
                w.z = (short)f2bf(p[j].z); w.w = (short)f2bf(p[j].w);
                *(short4v*)(P + c * 72 + j * 16 + g * 4) = w;
            }
            const short8 pf0 = *(const short8*)(P + c * 72 + g * 8);
            const short8 pf1 = *(const short8*)(P + c * 72 + 32 + g * 8);
            // PV: A = V^T rows (d), B = P^T -> D[d][q]
            __builtin_amdgcn_s_setprio(1);
            #pragma unroll
            for (int dt = 0; dt < 4; ++dt) {
                oacc[dt] = MFMA16x16x32(vf0[dt], pf0, oacc[dt], 0, 0, 0);
                oacc[dt] = MFMA16x16x32(vf1[dt], pf1, oacc[dt], 0, 0, 0);
            }
            __builtin_amdgcn_s_setprio(0);
            __syncthreads();   // drains staging (vmcnt 0) + all waves done with buf cur
            cur ^= 1;
        }
        float lsum = lpart;
        lsum += __shfl_xor(lsum, 16);
        lsum += __shfl_xor(lsum, 32);
        const float li = 1.f / lsum;             // lane-local (col=q layout)
        #pragma unroll
        for (int dt = 0; dt < 4; ++dt) {
            short4v o;
            o.x = (short)f2bf(oacc[dt][0] * li);
            o.y = (short)f2bf(oacc[dt][1] * li);
            o.z = (short)f2bf(oacc[dt][2] * li);
            o.w = (short)f2bf(oacc[dt][3] * li);
            *(short4v*)(Ob + (size_t)(b * 1024 + qg) * 768 + h * 64 + dt * 16 + g * 4) = o;
        }
    }
#undef STAGE
}

extern "C" void kernel_launch(void* const* d_in, const int* in_sizes, int n_in,
                              void* d_out, int out_size, void* d_ws, size_t ws_size,
                              hipStream_t stream) {
    const float* hs = (const float*)d_in[0];   // [8,1024,768]
    const float* Wa = (const float*)d_in[1];   // [768,2304]
    const float* ba = (const float*)d_in[2];   // [2304]
    const float* Wp = (const float*)d_in[3];   // [768,768]
    const float* bp = (const float*)d_in[4];   // [768]
    float* out = (float*)d_out;                // out | K | V  (each NOUT fp32)

    u16* ws  = (u16*)d_ws;
    u16* Xbf = ws;                             // [8192][768]
    u16* WaT = Xbf + NOUT;                     // [2304][768]
    u16* WpT = WaT + 768 * 2304;               // [768][768]
    u16* Qbf = WpT + 768 * 768;                // [B,H,T,64] (pre-scaled by 0.125*log2e)
    u16* Kbf = Qbf + NOUT;                     // [B,H,T,64]
    u16* VTb = Kbf + NOUT;                     // [B,H,64,T]
    u16* Obf = VTb + NOUT;                     // [8192][768]

    cvt_bf16_kernel<<<NOUT / 1024, 256, 0, stream>>>(hs, Xbf, NOUT);
    transpose_bf16_kernel<<<dim3(2304 / 32, 768 / 32), 256, 0, stream>>>(Wa, WaT, 768, 2304);
    transpose_bf16_kernel<<<dim3(768 / 32, 768 / 32), 256, 0, stream>>>(Wp, WpT, 768, 768);
    gemm_k768_kernel<0><<<dim3(64, 18), 256, 0, stream>>>(
        Xbf, WaT, ba, Qbf, Kbf, VTb, out + NOUT, out + 2 * (size_t)NOUT, nullptr);
    attn_kernel<<<dim3(96, 8), 256, 0, stream>>>(Qbf, Kbf, VTb, Obf);
    gemm_k768_kernel<1><<<dim3(64, 6), 256, 0, stream>>>(
        Obf, WpT, bp, nullptr, nullptr, nullptr, nullptr, nullptr, out);
}